// Round 1
// baseline (941.006 us; speedup 1.0000x reference)
//
#include <hip/hip_runtime.h>
#include <math.h>

#define BS 4
#define CC 28          // total channels in obs / maps
#define NF 25          // 1 + NUM_SEM splat feature channels
#define HS 240
#define WSC 320
#define NPIX (HS*WSC)
#define VR 100
#define ZD 80
#define MC 480
#define NCELL (VR*VR)                  // 10000 xy cells per batch
#define NREC_MAX ((size_t)BS*NPIX*4)   // worst-case records

__device__ __forceinline__ float clip01(float v){ return fminf(fmaxf(v, 0.f), 1.f); }

// ---------------- shared geometry (identical in prep/scatter) ----------------
struct Geo {
    float wx[2], wy[2], wz[2];
    int   xi[2], yi[2], zi[2];
    bool  sx[2], sy[2];
};

__device__ __forceinline__ Geo compute_geo(const float* __restrict__ obs,
                                           const float* __restrict__ view_angles,
                                           int b, int pix){
    int j = pix % WSC;
    int i = pix / WSC;
    float depth = obs[((size_t)(b*CC + 3))*NPIX + pix];
    if (depth < 0.f) depth = 10000.f;
    const float FOCAL = 277.12812921102035f;
    float X = ((float)j - 159.5f) * depth / FOCAL;
    float Z = ((float)(HS-1-i) - 119.5f) * depth / FOCAL;
    float a = view_angles[b] * 0.017453292519943295f;
    float ca = cosf(a), sa = sinf(a);
    float Y2 = ca*depth - sa*Z;
    float Z2 = sa*depth + ca*Z + 155.f;   // + AGENT_HEIGHT
    float X2 = X + 250.f;                 // + SHIFT_X

    // replicate reference arithmetic chain exactly
    float px = ((X2/5.f - 50.f)/100.f*2.f)*50.f + 50.f;
    float py = ((Y2/5.f - 50.f)/100.f*2.f)*50.f + 50.f;
    float pz = ((Z2/5.f - 32.f)/80.f*2.f)*40.f + 40.f;

    Geo g;
    float fx = floorf(px), fy = floorf(py), fz = floorf(pz);
    {
        float p0 = fx, p1 = fx + 1.f;
        g.sx[0] = (p0 > 0.f) && (p0 < 100.f);
        g.sx[1] = (p1 > 0.f) && (p1 < 100.f);
        g.wx[0] = g.sx[0] ? (1.f - fabsf(px - p0)) : 0.f;
        g.wx[1] = g.sx[1] ? (1.f - fabsf(px - p1)) : 0.f;
        g.xi[0] = g.sx[0] ? (int)p0 : 0;
        g.xi[1] = g.sx[1] ? (int)p1 : 0;
    }
    {
        float p0 = fy, p1 = fy + 1.f;
        g.sy[0] = (p0 > 0.f) && (p0 < 100.f);
        g.sy[1] = (p1 > 0.f) && (p1 < 100.f);
        g.wy[0] = g.sy[0] ? (1.f - fabsf(py - p0)) : 0.f;
        g.wy[1] = g.sy[1] ? (1.f - fabsf(py - p1)) : 0.f;
        g.yi[0] = g.sy[0] ? (int)p0 : 0;
        g.yi[1] = g.sy[1] ? (int)p1 : 0;
    }
    {
        float p0 = fz, p1 = fz + 1.f;
        bool s0 = (p0 > 0.f) && (p0 < 80.f);
        bool s1 = (p1 > 0.f) && (p1 < 80.f);
        g.wz[0] = s0 ? (1.f - fabsf(pz - p0)) : 0.f;
        g.wz[1] = s1 ? (1.f - fabsf(pz - p1)) : 0.f;
        g.zi[0] = s0 ? (int)p0 : 0;
        g.zi[1] = s1 ? (int)p1 : 0;
    }
    return g;
}

// ---------------- pose + sampling params ----------------
__global__ void pose_kernel(const float* __restrict__ pose_obs,
                            const float* __restrict__ poses_last,
                            float* __restrict__ out_p1,
                            float* __restrict__ out_p2,
                            float* __restrict__ params){
    int b = threadIdx.x;
    if (b >= BS) return;
    const float R2D = 57.29577951308232f;
    float th0 = poses_last[b*3+2] / R2D;
    float s0 = sinf(th0), c0 = cosf(th0);
    float ny = poses_last[b*3+1] + pose_obs[b*3+0]*s0 + pose_obs[b*3+1]*c0;
    float nx = poses_last[b*3+0] + pose_obs[b*3+0]*c0 - pose_obs[b*3+1]*s0;
    float no = poses_last[b*3+2] + pose_obs[b*3+2]*R2D;
    no = fmodf(no - 180.f, 360.f) + 180.f;
    no = fmodf(no + 180.f, 360.f) - 180.f;
    out_p1[b*3+0] = nx; out_p1[b*3+1] = ny; out_p1[b*3+2] = no;
    out_p2[b*3+0] = nx; out_p2[b*3+1] = ny; out_p2[b*3+2] = no;
    const float half = 240.f;
    float sx = -(nx*100.f/5.f - half)/half;
    float sy = -(ny*100.f/5.f - half)/half;
    float t = (90.f - no) * 0.017453292519943295f;
    params[b*4+0] = cosf(t);
    params[b*4+1] = sinf(t);
    params[b*4+2] = sx;
    params[b*4+3] = sy;
}

// ---------------- pass A: count records + transpose features ----------------
// grid = BS*NPIX/256 blocks (NPIX % 256 == 0, so a block never straddles batches)
__global__ __launch_bounds__(256)
void prep_kernel(const float* __restrict__ obs,
                 const float* __restrict__ view_angles,
                 int* __restrict__ counts,
                 float* __restrict__ feat){
    __shared__ float sf[6400];          // 256 px * 24 f, padded stride 25
    int t   = threadIdx.x;
    int tid = blockIdx.x * 256 + t;
    int b   = tid / NPIX;
    int pix = tid % NPIX;

    Geo g = compute_geo(obs, view_angles, b, pix);
    #pragma unroll
    for (int cy = 0; cy < 2; ++cy)
    #pragma unroll
    for (int cx = 0; cx < 2; ++cx){
        if (g.sx[cx] && g.sy[cy] && (g.wx[cx]*g.wy[cy] != 0.f))
            atomicAdd(&counts[b*NCELL + g.yi[cy]*VR + g.xi[cx]], 1);
    }

    // stage this block's 256x24 feature slab in LDS (pad 25 -> conflict-free)
    #pragma unroll 6
    for (int f = 0; f < 24; ++f)
        sf[t*25 + f] = obs[((size_t)(b*CC + 4 + f))*NPIX + pix];
    __syncthreads();
    // linear coalesced write-out: feat[((b*NPIX)+pix)*24 + f]
    size_t base = ((size_t)b*NPIX + (size_t)(pix - t)) * 24;
    for (int q = t; q < 6144; q += 256)
        feat[base + q] = sf[q + q/24];
}

// ---------------- pass B: exclusive scan over 40000 counts ----------------
__global__ void scan_kernel(const int* __restrict__ counts,
                            int* __restrict__ bases,
                            int* __restrict__ cursor){
    __shared__ int part[1024];
    int t = threadIdx.x;
    const int TOT = BS*NCELL;       // 40000
    const int CH  = 40;
    int beg = t*CH;
    int s = 0;
    for (int i = 0; i < CH; ++i){
        int idx = beg + i;
        if (idx < TOT) s += counts[idx];
    }
    part[t] = s;
    __syncthreads();
    for (int off = 1; off < 1024; off <<= 1){
        int v = (t >= off) ? part[t-off] : 0;
        __syncthreads();
        part[t] += v;
        __syncthreads();
    }
    int run = (t == 0) ? 0 : part[t-1];
    for (int i = 0; i < CH; ++i){
        int idx = beg + i;
        if (idx < TOT){
            bases[idx]  = run;
            cursor[idx] = run;
            run += counts[idx];
        }
    }
}

// ---------------- pass C: scatter self-contained records ----------------
// record = {w0 = (wx*wy)*wz0, w1 = (wx*wy)*wz1, pix|z0<<17|z1<<24, 0}
__global__ __launch_bounds__(256)
void scatter_kernel(const float* __restrict__ obs,
                    const float* __restrict__ view_angles,
                    int* __restrict__ cursor,
                    uint4* __restrict__ records){
    int tid = blockIdx.x * 256 + threadIdx.x;
    int b   = tid / NPIX;
    int pix = tid % NPIX;
    Geo g = compute_geo(obs, view_angles, b, pix);
    #pragma unroll
    for (int cy = 0; cy < 2; ++cy)
    #pragma unroll
    for (int cx = 0; cx < 2; ++cx){
        float wxy = g.wx[cx] * g.wy[cy];
        if (g.sx[cx] && g.sy[cy] && (wxy != 0.f)){
            int cid = b*NCELL + g.yi[cy]*VR + g.xi[cx];
            int pos = atomicAdd(&cursor[cid], 1);
            float w0 = wxy * g.wz[0];        // matches ref (wx*wy)*wz order
            float w1 = wxy * g.wz[1];
            unsigned iw = (unsigned)pix | ((unsigned)g.zi[0] << 17)
                                        | ((unsigned)g.zi[1] << 24);
            records[pos] = make_uint4(__float_as_uint(w0), __float_as_uint(w1), iw, 0u);
        }
    }
}

// ---------------- pass D: per-cell LDS accumulation + z-projection ----------------
// v2: records staged into LDS in coalesced 256-chunks; feat gathers batched 4x
// to break the record->feat dependent-latency chain (accum was latency-bound:
// VALUBusy 11.5%, HBM 5%, occupancy 79%).
__global__ __launch_bounds__(256)
void accum_kernel(const uint4* __restrict__ records,
                  const float* __restrict__ feat,
                  const int* __restrict__ bases,
                  const int* __restrict__ cursor,
                  float* __restrict__ ahp,
                  float* __restrict__ allp,
                  float* __restrict__ out0){
    __shared__ float col[ZD*NF];        // 2000 floats
    __shared__ uint4 srec[256];         // staged records (coalesced load)
    __shared__ float pall[200], pag[200];

    int cid = blockIdx.x;
    int b   = cid / NCELL;
    int rest = cid % NCELL;
    int y = rest / VR;
    int x = rest % VR;
    int t = threadIdx.x;

    for (int i = t; i < ZD*NF; i += 256) col[i] = 0.f;

    int start = bases[cid];
    int end   = cursor[cid];

    int r = t / NF;                     // record slot within group (0..9)
    int f = t % NF;
    bool act = t < 250;
    const float* feat_b = feat + (size_t)b*NPIX*24;

    for (int cb = start; cb < end; cb += 256){
        int n = end - cb; if (n > 256) n = 256;
        __syncthreads();                // srec safe to overwrite / col init done
        if (t < n) srec[t] = records[cb + t];   // fully coalesced 16B/lane
        __syncthreads();

        for (int sub = 0; sub < n; sub += 40){
            uint4 R[4];
            float V[4];
            bool  valid[4];
            #pragma unroll
            for (int u = 0; u < 4; ++u){
                int idx = sub + u*10 + r;
                valid[u] = act && (idx < n);
                R[u] = valid[u] ? srec[idx] : make_uint4(0u,0u,0u,0u);
            }
            // issue all independent feat gathers before any use (in-order
            // vmcnt return staggers the waits -> ~1 exposed miss per 40 recs)
            #pragma unroll
            for (int u = 0; u < 4; ++u){
                V[u] = 1.f;
                if (valid[u] && f != 0){
                    int pix = (int)(R[u].z & 0x1FFFFu);
                    V[u] = feat_b[(size_t)pix*24 + (f-1)];
                }
            }
            #pragma unroll
            for (int u = 0; u < 4; ++u){
                if (valid[u]){
                    float w0 = __uint_as_float(R[u].x);
                    float w1 = __uint_as_float(R[u].y);
                    unsigned iw = R[u].z;
                    int z0 = (int)((iw >> 17) & 0x7Fu);
                    int z1 = (int)((iw >> 24) & 0x7Fu);
                    if (w0 != 0.f) atomicAdd(&col[z0*NF + f], V[u] * w0);
                    if (w1 != 0.f) atomicAdd(&col[z1*NF + f], V[u] * w1);
                }
            }
        }
    }
    __syncthreads();

    // projection: 200 threads = 25 f x 8 z-groups of 10
    if (t < 200){
        int ff = t % NF;
        int gq = t / NF;
        float sall = 0.f, sag = 0.f;
        for (int z = gq*10; z < gq*10 + 10; ++z){
            float rv = rintf(col[z*NF + ff]);
            sall += rv;
            if (z >= 11 && z < 49) sag += rv;   // agent-height z range
        }
        pall[t] = sall;
        pag[t]  = sag;
    }
    __syncthreads();
    if (t < NF){
        float a = 0.f, s = 0.f;
        #pragma unroll
        for (int gq = 0; gq < 8; ++gq){
            s += pall[gq*NF + t];
            a += pag[gq*NF + t];
        }
        ahp[(((size_t)b*NF + t)*VR + y)*VR + x] = a;
        if (t == 0){
            allp[((size_t)b*VR + y)*VR + x] = s;
            out0[(size_t)b*NCELL + y*VR + x] = clip01(a);   // fp_map_pred
        }
    }
}

// ---------------- fused rotate+translate grid_sample + max ----------------
__global__ __launch_bounds__(256)
void final_kernel(const float* __restrict__ ahp,
                  const float* __restrict__ allp,
                  const float* __restrict__ params,
                  const float* __restrict__ maps_last,
                  float* __restrict__ out1){
    int tid = blockIdx.x * blockDim.x + threadIdx.x;
    if (tid >= BS*MC*MC) return;
    int w = tid % MC;
    int h = (tid / MC) % MC;
    int b = tid / (MC*MC);

    float ct = params[b*4+0], st = params[b*4+1];
    float sx = params[b*4+2], sy = params[b*4+3];

    float gx = -1.f + 2.f*(float)w/479.f;
    float gy = -1.f + 2.f*(float)h/479.f;
    float ix = (gx + sx + 1.f)*0.5f*479.f;
    float iy = (gy + sy + 1.f)*0.5f*479.f;
    float x0 = floorf(ix), y0 = floorf(iy);
    float wx1 = ix - x0, wx0 = 1.f - wx1;
    float wy1 = iy - y0, wy0 = 1.f - wy1;

    int   offs[16];
    float wt16[16];
    int nz = 0;
    #pragma unroll
    for (int tc = 0; tc < 4; ++tc){
        float txf = (tc & 1) ? x0 + 1.f : x0;
        float tyf = (tc & 2) ? y0 + 1.f : y0;
        float wt  = ((tc & 1) ? wx1 : wx0) * ((tc & 2) ? wy1 : wy0);
        bool validT = (txf >= 0.f) && (txf <= 479.f) && (tyf >= 0.f) && (tyf <= 479.f);
        int txc = (int)fminf(fmaxf(txf, 0.f), 479.f);
        int tyc = (int)fminf(fmaxf(tyf, 0.f), 479.f);

        float gx2 = -1.f + 2.f*(float)txc/479.f;
        float gy2 = -1.f + 2.f*(float)tyc/479.f;
        float rgx = ct*gx2 - st*gy2;
        float rgy = st*gx2 + ct*gy2;
        float ixr = (rgx + 1.f)*0.5f*479.f;
        float iyr = (rgy + 1.f)*0.5f*479.f;
        float rx0 = floorf(ixr), ry0 = floorf(iyr);
        float rwx1 = ixr - rx0, rwx0 = 1.f - rwx1;
        float rwy1 = iyr - ry0, rwy0 = 1.f - rwy1;

        #pragma unroll
        for (int rc = 0; rc < 4; ++rc){
            int id = tc*4 + rc;
            float rxf = (rc & 1) ? rx0 + 1.f : rx0;
            float ryf = (rc & 2) ? ry0 + 1.f : ry0;
            float wr  = ((rc & 1) ? rwx1 : rwx0) * ((rc & 2) ? rwy1 : rwy0);
            bool validR = (rxf >= 0.f) && (rxf <= 479.f) && (ryf >= 0.f) && (ryf <= 479.f);
            int rxc = (int)fminf(fmaxf(rxf, 0.f), 479.f);
            int ryc = (int)fminf(fmaxf(ryf, 0.f), 479.f);
            bool inwin = validT && validR &&
                         (rxc >= 190) && (rxc < 290) && (ryc >= 240) && (ryc < 336);
            float wgt = wt * wr;
            if (inwin && wgt != 0.f){
                offs[id] = (ryc - 240)*VR + (rxc - 190);
                wt16[id] = wgt;
                nz++;
            } else {
                offs[id] = -1;
                wt16[id] = 0.f;
            }
        }
    }

    size_t outBase = (size_t)b*CC*MC*MC + (size_t)h*MC + w;
    if (nz == 0){
        #pragma unroll
        for (int ch = 0; ch < CC; ++ch){
            size_t o = outBase + (size_t)ch*MC*MC;
            out1[o] = fmaxf(maps_last[o], 0.f);
        }
        return;
    }

    const float* ahp_b  = ahp  + (size_t)b*NF*VR*VR;
    const float* allp_b = allp + (size_t)b*VR*VR;
    for (int ch = 0; ch < CC; ++ch){
        float acc = 0.f;
        if (ch != 2 && ch != 3){
            #pragma unroll
            for (int id = 0; id < 16; ++id){
                if (offs[id] >= 0){
                    float v;
                    if (ch == 0)      v = clip01(ahp_b[offs[id]]);
                    else if (ch == 1) v = clip01(allp_b[offs[id]]);
                    else              v = clip01(ahp_b[(size_t)(ch-3)*VR*VR + offs[id]] / 5.f);
                    acc += wt16[id] * v;
                }
            }
        }
        size_t o = outBase + (size_t)ch*MC*MC;
        out1[o] = fmaxf(maps_last[o], acc);
    }
}

extern "C" void kernel_launch(void* const* d_in, const int* in_sizes, int n_in,
                              void* d_out, int out_size, void* d_ws, size_t ws_size,
                              hipStream_t stream){
    const float* obs         = (const float*)d_in[0];
    const float* pose_obs    = (const float*)d_in[1];
    const float* maps_last   = (const float*)d_in[2];
    const float* poses_last  = (const float*)d_in[3];
    const float* view_angles = (const float*)d_in[4];
    float* out = (float*)d_out;

    const size_t OUT0 = (size_t)BS*VR*VR;        // 40000
    const size_t OUT1 = (size_t)BS*CC*MC*MC;     // 25,804,800
    float* out0 = out;
    float* out1 = out + OUT0;
    float* out2 = out + OUT0 + OUT1;
    float* out3 = out2 + BS*3;

    const size_t AHP_FLOATS  = (size_t)BS*NF*VR*VR;   // 1,000,000
    const size_t ALLP_FLOATS = (size_t)BS*VR*VR;      // 40,000
    const size_t NCID        = (size_t)BS*NCELL;      // 40,000
    const size_t FEAT_FLOATS = (size_t)BS*NPIX*24;    // 7,372,800 (29.5 MB)

    // small arrays read by final_kernel — always in ws
    float* ahp    = (float*)d_ws;
    float* allp   = ahp  + AHP_FLOATS;
    float* params = allp + ALLP_FLOATS;
    char*  ws_tail = (char*)(params + 16);
    size_t ws_used_small = (size_t)(ws_tail - (char*)d_ws);

    // big transient arrays: counts/bases/cursor + records + feat
    const size_t BIG_BYTES = NCID*3*4 + 32 + NREC_MAX*16 + FEAT_FLOATS*4;  // ~49.7 MB
    char* big;
    if (ws_size >= ws_used_small + BIG_BYTES){
        big = ws_tail;
    } else {
        // place in the tail of out1 (fully consumed before final_kernel writes out1)
        big = (char*)(out1 + OUT1) - BIG_BYTES;
        big = (char*)((uintptr_t)big & ~(uintptr_t)15);
    }
    int* counts = (int*)big;
    int* bases  = counts + NCID;
    int* cursor = bases  + NCID;
    uint4* records = (uint4*)(((uintptr_t)(cursor + NCID) + 15) & ~(uintptr_t)15);
    float* feat    = (float*)(records + NREC_MAX);

    hipMemsetAsync(counts, 0, NCID*4, stream);
    pose_kernel<<<1, 64, 0, stream>>>(pose_obs, poses_last, out2, out3, params);

    int nblk = (BS*NPIX)/256;   // 1200, exact
    prep_kernel<<<nblk, 256, 0, stream>>>(obs, view_angles, counts, feat);
    scan_kernel<<<1, 1024, 0, stream>>>(counts, bases, cursor);
    scatter_kernel<<<nblk, 256, 0, stream>>>(obs, view_angles, cursor, records);
    accum_kernel<<<(int)NCID, 256, 0, stream>>>(records, feat, bases, cursor,
                                                ahp, allp, out0);
    final_kernel<<<(BS*MC*MC + 255)/256, 256, 0, stream>>>(ahp, allp, params,
                                                           maps_last, out1);
}